// Round 4
// baseline (1654.367 us; speedup 1.0000x reference)
//
#include <hip/hip_runtime.h>

#define DIM 128
#define BROWS 128               // rows per bucket (rows>>7)
#define BCAP 3072               // edata capacity per bucket (mean 2046, +22 sigma)
#define BK_EDGES 8192           // edges per k_bucket block

typedef __attribute__((ext_vector_type(8))) short short8;   // 8 x bf16 (4 VGPR)
typedef __attribute__((ext_vector_type(4))) float f32x4;    // 4 x f32  (4 VGPR)

__device__ __forceinline__ unsigned short f2bf(float f) {   // RNE fp32->bf16
    unsigned u = __float_as_uint(f);
    u += 0x7fffu + ((u >> 16) & 1u);
    return (unsigned short)(u >> 16);
}
__device__ __forceinline__ float bf2f(unsigned short b) {
    return __uint_as_float(((unsigned)b) << 16);
}

// ---- prep: W1 [128,128], W2 [128,256] fp32 -> bf16 ([n][k] row-major = B-frag order) ----
__global__ void k_prep(const float* __restrict__ W1, const float* __restrict__ W2,
                       unsigned short* __restrict__ w1b, unsigned short* __restrict__ w2b) {
    int idx = blockIdx.x * 256 + threadIdx.x;       // 192*256 = 49152 = 16384 + 32768
    if (idx < 16384)      w1b[idx] = f2bf(W1[idx]);
    else                  w2b[idx - 16384] = f2bf(W2[idx - 16384]);
}

// ---- convert input fp32 -> bf16 ----
__global__ void k_cvt(const float4* __restrict__ in, unsigned short* __restrict__ outb, int n4) {
    int i = blockIdx.x * 256 + threadIdx.x;
    if (i < n4) {
        float4 v = in[i];
        *(ushort4*)(outb + (long)i * 4) =
            make_ushort4(f2bf(v.x), f2bf(v.y), f2bf(v.z), f2bf(v.w));
    }
}

__global__ void k_zero_cur(int* __restrict__ gcur, int nbuk) {
    int i = blockIdx.x * 256 + threadIdx.x;
    if (i < nbuk) gcur[i] = 0;
}

// ---- one-pass bucket scatter: per block, LDS hist -> chunk reserve -> compact writes ----
// edata[b*BCAP + pos] = ( (row&127)<<17 | col , val )
__global__ __launch_bounds__(256) void k_bucket(const int* __restrict__ er,
                                                const int* __restrict__ ec,
                                                const float* __restrict__ ev,
                                                int* __restrict__ gcur,
                                                int2* __restrict__ edata, int E, int nbuk) {
    __shared__ int lhist[800];
    __shared__ int lpos[800];
    for (int b = threadIdx.x; b < nbuk; b += 256) lhist[b] = 0;
    __syncthreads();
    int e0 = blockIdx.x * BK_EDGES;
    for (int j = 0; j < BK_EDGES; j += 256) {
        int e = e0 + j + threadIdx.x;
        if (e < E) atomicAdd(&lhist[er[e] >> 7], 1);
    }
    __syncthreads();
    for (int b = threadIdx.x; b < nbuk; b += 256) {
        int c = lhist[b];
        int g = (c > 0) ? atomicAdd(&gcur[b], c) : 0;
        lpos[b] = b * BCAP + g;         // running write cursor for this block's chunk
    }
    __syncthreads();
    for (int j = 0; j < BK_EDGES; j += 256) {
        int e = e0 + j + threadIdx.x;
        if (e < E) {
            int r = er[e], b = r >> 7;
            int p = atomicAdd(&lpos[b], 1);
            if (p < (b + 1) * BCAP)     // capacity guard (never triggers at 22 sigma)
                edata[p] = make_int2(((r & 127) << 17) | ec[e], __float_as_int(ev[e]));
        }
    }
}

// ---- gather: one block per bucket; accumulate val * x[col] into 64 KB LDS tile ----
__global__ __launch_bounds__(256) void k_gather_lds(const unsigned short* __restrict__ xb,
                                                    const int2* __restrict__ edata,
                                                    const int* __restrict__ gcur,
                                                    unsigned short* __restrict__ aggb, int N) {
    __shared__ float agg[BROWS * DIM];              // 64 KB
    int b = blockIdx.x;
    int tid = threadIdx.x, lane = tid & 63, w = tid >> 6;
    float4* a4 = (float4*)agg;
    for (int i = tid; i < BROWS * DIM / 4; i += 256) a4[i] = make_float4(0.f, 0.f, 0.f, 0.f);
    __syncthreads();
    int cnt = gcur[b]; if (cnt > BCAP) cnt = BCAP;
    const int2* ed = edata + (long)b * BCAP;
    for (int p = w * 64; p < cnt; p += 256) {
        int nc = cnt - p; if (nc > 64) nc = 64;
        int2 e2 = (lane < nc) ? ed[p + lane] : make_int2(0, 0);
        for (int j = 0; j < nc; ++j) {
            int pk = __shfl(e2.x, j);
            float v = __int_as_float(__shfl(e2.y, j));
            int col = pk & 0x1FFFF, rl = pk >> 17;
            float x0 = bf2f(xb[(long)col * DIM + lane]);        // dims [lane]
            float x1 = bf2f(xb[(long)col * DIM + 64 + lane]);   // dims [lane+64]
            atomicAdd(&agg[rl * DIM + lane], v * x0);           // bank = lane&31: 2-way, free
            atomicAdd(&agg[rl * DIM + 64 + lane], v * x1);
        }
    }
    __syncthreads();
    int r0 = b * BROWS;
    for (int i = tid; i < BROWS * DIM / 2; i += 256) {          // 2 floats per thread-iter
        int r = i >> 6, c = (i & 63) * 2;
        int row = r0 + r;
        if (row < N) {
            float f0 = agg[r * DIM + c], f1 = agg[r * DIM + c + 1];
            *(ushort2*)(aggb + (long)row * DIM + c) = make_ushort2(f2bf(f0), f2bf(f1));
        }
    }
}

// ---- fused MFMA: out = leaky_relu([x+agg@W1^T, x*(agg@W1^T)] @ W2^T) ----
__global__ __launch_bounds__(256) void k_fused(const unsigned short* __restrict__ aggb,
                                               const unsigned short* __restrict__ inputb,
                                               const unsigned short* __restrict__ w1b,
                                               const unsigned short* __restrict__ w2b,
                                               float* __restrict__ out, int N) {
    __shared__ __align__(16) unsigned short sh[2 * 64 * 136];   // h0 | h1, rows padded to 136
    int w = threadIdx.x >> 6, lane = threadIdx.x & 63;
    int quad = lane >> 4, lq = lane & 15;
    int m0 = blockIdx.x * 64 + w * 16;

    // gemm1: A direct bf16 loads from aggb; B direct from global bf16 weights
    short8 afr[4];
    {
        int row = m0 + lq; if (row >= N) row = N - 1;
#pragma unroll
        for (int kb = 0; kb < 4; ++kb)
            afr[kb] = *(const short8*)(aggb + (long)row * DIM + kb * 32 + quad * 8);
    }
    f32x4 neigh[8];
#pragma unroll
    for (int nt = 0; nt < 8; ++nt) {
        f32x4 c = {0.f, 0.f, 0.f, 0.f};
#pragma unroll
        for (int kb = 0; kb < 4; ++kb) {
            short8 b = *(const short8*)(w1b + (nt * 16 + lq) * DIM + kb * 32 + quad * 8);
            c = __builtin_amdgcn_mfma_f32_16x16x32_bf16(afr[kb], b, c, 0, 0, 0);
        }
        neigh[nt] = c;
    }

    // h phase: C-layout regs + bf16 x -> bf16 h -> wave-private LDS rows
    unsigned short* sh0 = sh;
    unsigned short* sh1 = sh + 64 * 136;
#pragma unroll
    for (int nt = 0; nt < 8; ++nt) {
#pragma unroll
        for (int rg = 0; rg < 4; ++rg) {
            int r = m0 + quad * 4 + rg;
            int rr = (r < N) ? r : (N - 1);
            float x = bf2f(inputb[(long)rr * DIM + nt * 16 + lq]);
            float nb = neigh[nt][rg];
            int off = (w * 16 + quad * 4 + rg) * 136 + nt * 16 + lq;
            sh0[off] = f2bf(x + nb);
            sh1[off] = f2bf(x * nb);
        }
    }

    // gemm2 (K=256 over two h halves) + leaky_relu epilogue
    int arow = (w * 16 + lq) * 136;
#pragma unroll
    for (int nt = 0; nt < 8; ++nt) {
        f32x4 c = {0.f, 0.f, 0.f, 0.f};
#pragma unroll
        for (int kb = 0; kb < 4; ++kb) {
            short8 a = *(const short8*)(sh0 + arow + kb * 32 + quad * 8);
            short8 b = *(const short8*)(w2b + (nt * 16 + lq) * 256 + kb * 32 + quad * 8);
            c = __builtin_amdgcn_mfma_f32_16x16x32_bf16(a, b, c, 0, 0, 0);
        }
#pragma unroll
        for (int kb = 0; kb < 4; ++kb) {
            short8 a = *(const short8*)(sh1 + arow + kb * 32 + quad * 8);
            short8 b = *(const short8*)(w2b + (nt * 16 + lq) * 256 + 128 + kb * 32 + quad * 8);
            c = __builtin_amdgcn_mfma_f32_16x16x32_bf16(a, b, c, 0, 0, 0);
        }
#pragma unroll
        for (int rg = 0; rg < 4; ++rg) {
            int r = m0 + quad * 4 + rg;
            if (r < N) {
                float v = c[rg];
                v = (v > 0.f) ? v : 0.01f * v;
                out[(long)r * DIM + nt * 16 + lq] = v;
            }
        }
    }
}

extern "C" void kernel_launch(void* const* d_in, const int* in_sizes, int n_in,
                              void* d_out, int out_size, void* d_ws, size_t ws_size,
                              hipStream_t stream) {
    const float* input = (const float*)d_in[0];
    const int*   er    = (const int*)d_in[1];
    const int*   ec    = (const int*)d_in[2];
    const float* ev    = (const float*)d_in[3];
    const float* W1    = (const float*)d_in[4];
    const float* W2    = (const float*)d_in[5];
    int N = in_sizes[0] / DIM;      // 100000
    int E = in_sizes[1];            // 1600000
    float* out = (float*)d_out;
    int nbuk = (N + BROWS - 1) / BROWS;     // 782

    // ---- workspace layout (~45 MB, all chunks 16B-aligned) ----
    int* ws = (int*)d_ws;
    int* gcur = ws;                                                      // nbuk ints
    int2* edata = (int2*)(ws + 1024);                                    // nbuk*BCAP int2
    unsigned short* w1b = (unsigned short*)(edata + (long)nbuk * BCAP);  // 16384 bf16
    unsigned short* w2b = w1b + 16384;                                   // 32768 bf16
    unsigned short* inputb = w2b + 32768;                                // N*DIM bf16
    unsigned short* aggb = inputb + (long)N * DIM;                       // N*DIM bf16

    k_prep<<<192, 256, 0, stream>>>(W1, W2, w1b, w2b);
    int n4 = N * (DIM / 4);
    k_cvt<<<(n4 + 255) / 256, 256, 0, stream>>>((const float4*)input, inputb, n4);
    k_zero_cur<<<(nbuk + 255) / 256, 256, 0, stream>>>(gcur, nbuk);

    k_bucket<<<(E + BK_EDGES - 1) / BK_EDGES, 256, 0, stream>>>(
        er, ec, ev, gcur, edata, E, nbuk);

    k_gather_lds<<<nbuk, 256, 0, stream>>>(inputb, edata, gcur, aggb, N);

    k_fused<<<(N + 63) / 64, 256, 0, stream>>>(aggb, inputb, w1b, w2b, out, N);
}

// Round 5
// 372.196 us; speedup vs baseline: 4.4449x; 4.4449x over previous
//
#include <hip/hip_runtime.h>

#define DIM 128
#define BROWS 128               // rows per bucket (row >> 7)
#define BCAP 3072               // edata capacity per bucket (mean 2046, +22 sigma)
#define BK_EDGES 8192           // edges per k_bucket block

typedef __attribute__((ext_vector_type(8))) short short8;   // 8 x bf16 (4 VGPR)
typedef __attribute__((ext_vector_type(4))) float f32x4;    // 4 x f32  (4 VGPR)

__device__ __forceinline__ unsigned short f2bf(float f) {   // RNE fp32->bf16
    unsigned u = __float_as_uint(f);
    u += 0x7fffu + ((u >> 16) & 1u);
    return (unsigned short)(u >> 16);
}
__device__ __forceinline__ float bf2f(unsigned short b) {
    return __uint_as_float(((unsigned)b) << 16);
}

// ---- prep: W1 [128,128], W2 [128,256] fp32 -> bf16 ([n][k] row-major = B-frag order) ----
__global__ void k_prep(const float* __restrict__ W1, const float* __restrict__ W2,
                       unsigned short* __restrict__ w1b, unsigned short* __restrict__ w2b) {
    int idx = blockIdx.x * 256 + threadIdx.x;       // 192*256 = 49152 = 16384 + 32768
    if (idx < 16384)      w1b[idx] = f2bf(W1[idx]);
    else                  w2b[idx - 16384] = f2bf(W2[idx - 16384]);
}

// ---- convert input fp32 -> bf16 ----
__global__ void k_cvt(const float4* __restrict__ in, unsigned short* __restrict__ outb, int n4) {
    int i = blockIdx.x * 256 + threadIdx.x;
    if (i < n4) {
        float4 v = in[i];
        *(ushort4*)(outb + (long)i * 4) =
            make_ushort4(f2bf(v.x), f2bf(v.y), f2bf(v.z), f2bf(v.w));
    }
}

__global__ void k_zero_cur(int* __restrict__ gcur, int nbuk) {
    int i = blockIdx.x * 256 + threadIdx.x;
    if (i < nbuk) gcur[i] = 0;
}

// ---- pass 1: bucket scatter. Per block: LDS int hist -> chunk reserve -> compact writes ----
// edata[b*BCAP + pos] = ( (row&127)<<17 | col , val )    (col < 2^17)
__global__ __launch_bounds__(256) void k_bucket(const int* __restrict__ er,
                                                const int* __restrict__ ec,
                                                const float* __restrict__ ev,
                                                int* __restrict__ gcur,
                                                int2* __restrict__ edata, int E, int nbuk) {
    __shared__ int lhist[800];
    __shared__ int lpos[800];
    for (int b = threadIdx.x; b < nbuk; b += 256) lhist[b] = 0;
    __syncthreads();
    int e0 = blockIdx.x * BK_EDGES;
    for (int j = 0; j < BK_EDGES; j += 256) {
        int e = e0 + j + threadIdx.x;
        if (e < E) atomicAdd(&lhist[er[e] >> 7], 1);        // int LDS atomic: native
    }
    __syncthreads();
    for (int b = threadIdx.x; b < nbuk; b += 256) {
        int c = lhist[b];
        int g = (c > 0) ? atomicAdd(&gcur[b], c) : 0;
        lpos[b] = b * BCAP + g;         // running write cursor for this block's chunk
    }
    __syncthreads();
    for (int j = 0; j < BK_EDGES; j += 256) {
        int e = e0 + j + threadIdx.x;
        if (e < E) {
            int r = er[e], b = r >> 7;
            int p = atomicAdd(&lpos[b], 1);
            if (p < (b + 1) * BCAP)     // capacity guard (statistically never)
                edata[p] = make_int2(((r & 127) << 17) | ec[e], __float_as_int(ev[e]));
        }
    }
}

// ---- pass 2: per-bucket CSR sort, fully in LDS, written back in place ----
// After this, edata rows of bucket b are contiguous ascending-local-row; rs/re give segments.
__global__ __launch_bounds__(256) void k_csr(int2* __restrict__ edata,
                                             const int* __restrict__ gcur,
                                             int* __restrict__ rs, int* __restrict__ re) {
    __shared__ int2 sed[BCAP];          // 24 KB
    __shared__ int hist[BROWS];
    __shared__ int scan[BROWS];
    __shared__ int lcur[BROWS];
    int b = blockIdx.x, tid = threadIdx.x;
    int cnt = gcur[b]; if (cnt > BCAP) cnt = BCAP;
    int2* ed = edata + (long)b * BCAP;
    if (tid < BROWS) hist[tid] = 0;
    for (int i = tid; i < cnt; i += 256) sed[i] = ed[i];
    __syncthreads();
    for (int i = tid; i < cnt; i += 256) atomicAdd(&hist[sed[i].x >> 17], 1);
    __syncthreads();
    if (tid < BROWS) scan[tid] = hist[tid];
    __syncthreads();
    for (int off = 1; off < BROWS; off <<= 1) {             // Hillis-Steele inclusive
        int v = (tid < BROWS && tid >= off) ? scan[tid - off] : 0;
        __syncthreads();
        if (tid < BROWS) scan[tid] += v;
        __syncthreads();
    }
    if (tid < BROWS) {
        int excl = scan[tid] - hist[tid];
        lcur[tid] = excl;
        int row = b * BROWS + tid;                          // rs/re sized nbuk*BROWS
        rs[row] = b * BCAP + excl;
        re[row] = b * BCAP + excl + hist[tid];
    }
    __syncthreads();
    for (int i = tid; i < cnt; i += 256) {
        int2 v = sed[i];
        int p = atomicAdd(&lcur[v.x >> 17], 1);
        ed[p] = make_int2(v.x & 0x1FFFF, v.y);              // strip row bits: (col,val)
    }
}

// ---- gather: one wave per row (25K blocks — latency hidden by TLP), bf16 x ----
__global__ __launch_bounds__(256) void k_gather(const unsigned short* __restrict__ xb,
                                                const int2* __restrict__ edata,
                                                const int* __restrict__ rs,
                                                const int* __restrict__ re,
                                                unsigned short* __restrict__ aggb, int N) {
    int wave = threadIdx.x >> 6, lane = threadIdx.x & 63;
    int row = blockIdx.x * 4 + wave;
    if (row >= N) return;
    int beg = rs[row], end = re[row];
    float2 acc = make_float2(0.f, 0.f);
    for (int p = beg; p < end; p += 64) {
        int nc = end - p; if (nc > 64) nc = 64;
        int2 ed = (lane < nc) ? edata[p + lane] : make_int2(0, 0);
        for (int j = 0; j < nc; ++j) {
            int col = __shfl(ed.x, j);
            float v = __int_as_float(__shfl(ed.y, j));
            ushort2 x2 = *(const ushort2*)(xb + (long)col * DIM + lane * 2);
            acc.x += v * bf2f(x2.x);
            acc.y += v * bf2f(x2.y);
        }
    }
    *(ushort2*)(aggb + (long)row * DIM + lane * 2) = make_ushort2(f2bf(acc.x), f2bf(acc.y));
}

// ---- fused MFMA: out = leaky_relu([x+agg@W1^T, x*(agg@W1^T)] @ W2^T) ----
// 64 rows/block, 4 waves, wave-private 16-row strip; LDS only for C->A layout round-trip.
__global__ __launch_bounds__(256) void k_fused(const unsigned short* __restrict__ aggb,
                                               const unsigned short* __restrict__ inputb,
                                               const unsigned short* __restrict__ w1b,
                                               const unsigned short* __restrict__ w2b,
                                               float* __restrict__ out, int N) {
    __shared__ __align__(16) unsigned short sh[2 * 64 * 136];   // h0 | h1, rows padded to 136
    int w = threadIdx.x >> 6, lane = threadIdx.x & 63;
    int quad = lane >> 4, lq = lane & 15;
    int m0 = blockIdx.x * 64 + w * 16;

    // gemm1: A direct bf16 loads from aggb; B direct from global bf16 weights (L2-resident)
    short8 afr[4];
    {
        int row = m0 + lq; if (row >= N) row = N - 1;
#pragma unroll
        for (int kb = 0; kb < 4; ++kb)
            afr[kb] = *(const short8*)(aggb + (long)row * DIM + kb * 32 + quad * 8);
    }
    f32x4 neigh[8];
#pragma unroll
    for (int nt = 0; nt < 8; ++nt) {
        f32x4 c = {0.f, 0.f, 0.f, 0.f};
#pragma unroll
        for (int kb = 0; kb < 4; ++kb) {
            short8 b = *(const short8*)(w1b + (nt * 16 + lq) * DIM + kb * 32 + quad * 8);
            c = __builtin_amdgcn_mfma_f32_16x16x32_bf16(afr[kb], b, c, 0, 0, 0);
        }
        neigh[nt] = c;
    }

    // h phase: C-layout regs + bf16 x -> bf16 h -> wave-private LDS rows
    unsigned short* sh0 = sh;
    unsigned short* sh1 = sh + 64 * 136;
#pragma unroll
    for (int nt = 0; nt < 8; ++nt) {
#pragma unroll
        for (int rg = 0; rg < 4; ++rg) {
            int r = m0 + quad * 4 + rg;
            int rr = (r < N) ? r : (N - 1);
            float x = bf2f(inputb[(long)rr * DIM + nt * 16 + lq]);
            float nb = neigh[nt][rg];
            int off = (w * 16 + quad * 4 + rg) * 136 + nt * 16 + lq;
            sh0[off] = f2bf(x + nb);
            sh1[off] = f2bf(x * nb);
        }
    }

    // gemm2 (K=256 over two h halves) + leaky_relu epilogue, direct store
    int arow = (w * 16 + lq) * 136;
#pragma unroll
    for (int nt = 0; nt < 8; ++nt) {
        f32x4 c = {0.f, 0.f, 0.f, 0.f};
#pragma unroll
        for (int kb = 0; kb < 4; ++kb) {
            short8 a = *(const short8*)(sh0 + arow + kb * 32 + quad * 8);
            short8 b = *(const short8*)(w2b + (nt * 16 + lq) * 256 + kb * 32 + quad * 8);
            c = __builtin_amdgcn_mfma_f32_16x16x32_bf16(a, b, c, 0, 0, 0);
        }
#pragma unroll
        for (int kb = 0; kb < 4; ++kb) {
            short8 a = *(const short8*)(sh1 + arow + kb * 32 + quad * 8);
            short8 b = *(const short8*)(w2b + (nt * 16 + lq) * 256 + 128 + kb * 32 + quad * 8);
            c = __builtin_amdgcn_mfma_f32_16x16x32_bf16(a, b, c, 0, 0, 0);
        }
#pragma unroll
        for (int rg = 0; rg < 4; ++rg) {
            int r = m0 + quad * 4 + rg;
            if (r < N) {
                float v = c[rg];
                v = (v > 0.f) ? v : 0.01f * v;
                out[(long)r * DIM + nt * 16 + lq] = v;
            }
        }
    }
}

extern "C" void kernel_launch(void* const* d_in, const int* in_sizes, int n_in,
                              void* d_out, int out_size, void* d_ws, size_t ws_size,
                              hipStream_t stream) {
    const float* input = (const float*)d_in[0];
    const int*   er    = (const int*)d_in[1];
    const int*   ec    = (const int*)d_in[2];
    const float* ev    = (const float*)d_in[3];
    const float* W1    = (const float*)d_in[4];
    const float* W2    = (const float*)d_in[5];
    int N = in_sizes[0] / DIM;      // 100000
    int E = in_sizes[1];            // 1600000
    float* out = (float*)d_out;
    int nbuk = (N + BROWS - 1) / BROWS;     // 782

    // ---- workspace layout (~71 MB, all chunks 16B-aligned) ----
    int* ws = (int*)d_ws;
    int* gcur = ws;                                                      // nbuk ints (pad 1024)
    int2* edata = (int2*)(ws + 1024);                                    // nbuk*BCAP int2
    int* rs = (int*)(edata + (long)nbuk * BCAP);                         // nbuk*BROWS ints
    int* re = rs + (long)nbuk * BROWS;                                   // nbuk*BROWS ints
    unsigned short* w1b = (unsigned short*)(re + (long)nbuk * BROWS);    // 16384 bf16
    unsigned short* w2b = w1b + 16384;                                   // 32768 bf16
    unsigned short* inputb = w2b + 32768;                                // N*DIM bf16
    unsigned short* aggb = inputb + (long)N * DIM;                       // N*DIM bf16

    k_prep<<<192, 256, 0, stream>>>(W1, W2, w1b, w2b);
    int n4 = N * (DIM / 4);
    k_cvt<<<(n4 + 255) / 256, 256, 0, stream>>>((const float4*)input, inputb, n4);
    k_zero_cur<<<(nbuk + 255) / 256, 256, 0, stream>>>(gcur, nbuk);

    k_bucket<<<(E + BK_EDGES - 1) / BK_EDGES, 256, 0, stream>>>(
        er, ec, ev, gcur, edata, E, nbuk);

    k_csr<<<nbuk, 256, 0, stream>>>(edata, gcur, rs, re);

    k_gather<<<(N + 3) / 4, 256, 0, stream>>>(inputb, edata, rs, re, aggb, N);

    k_fused<<<(N + 63) / 64, 256, 0, stream>>>(aggb, inputb, w1b, w2b, out, N);
}

// Round 6
// 320.982 us; speedup vs baseline: 5.1541x; 1.1596x over previous
//
#include <hip/hip_runtime.h>

#define DIM 128
#define BROWS 128               // rows per bucket (row >> 7)
#define BCAP 3072               // edata capacity per bucket (mean 2046, +22 sigma)
#define BK_EDGES 2048           // edges per k_bucket block (782 blocks -> full CU spread)

typedef __attribute__((ext_vector_type(8))) short short8;   // 8 x bf16 (4 VGPR)
typedef __attribute__((ext_vector_type(4))) float f32x4;    // 4 x f32  (4 VGPR)

__device__ __forceinline__ unsigned short f2bf(float f) {   // RNE fp32->bf16
    unsigned u = __float_as_uint(f);
    u += 0x7fffu + ((u >> 16) & 1u);
    return (unsigned short)(u >> 16);
}
__device__ __forceinline__ float bf2f(unsigned short b) {
    return __uint_as_float(((unsigned)b) << 16);
}

// ---- merged pre-pass: input fp32->bf16, W1/W2 fp32->bf16, zero gcur (one launch) ----
__global__ void k_pre(const float4* __restrict__ in, const float* __restrict__ W1,
                      const float* __restrict__ W2, unsigned short* __restrict__ inputb,
                      unsigned short* __restrict__ w1b, unsigned short* __restrict__ w2b,
                      int* __restrict__ gcur, int n4, int nCvt, int nbuk) {
    int b = blockIdx.x;
    if (b < nCvt) {
        int i = b * 256 + threadIdx.x;
        if (i < n4) {
            float4 v = in[i];
            *(ushort4*)(inputb + (long)i * 4) =
                make_ushort4(f2bf(v.x), f2bf(v.y), f2bf(v.z), f2bf(v.w));
        }
    } else if (b < nCvt + 192) {
        int idx = (b - nCvt) * 256 + threadIdx.x;   // 49152 = 16384 + 32768
        if (idx < 16384)      w1b[idx] = f2bf(W1[idx]);
        else                  w2b[idx - 16384] = f2bf(W2[idx - 16384]);
    } else {
        int i = (b - nCvt - 192) * 256 + threadIdx.x;
        if (i < nbuk) gcur[i] = 0;
    }
}

// ---- pass 1: bucket scatter. Per block: LDS int hist -> chunk reserve -> compact writes ----
// edata[b*BCAP + pos] = ( (row&127)<<17 | col , val )    (col < 2^17)
__global__ __launch_bounds__(256) void k_bucket(const int* __restrict__ er,
                                                const int* __restrict__ ec,
                                                const float* __restrict__ ev,
                                                int* __restrict__ gcur,
                                                int2* __restrict__ edata, int E, int nbuk) {
    __shared__ int lhist[800];
    __shared__ int lpos[800];
    for (int b = threadIdx.x; b < nbuk; b += 256) lhist[b] = 0;
    __syncthreads();
    int e0 = blockIdx.x * BK_EDGES;
    for (int j = 0; j < BK_EDGES; j += 256) {
        int e = e0 + j + threadIdx.x;
        if (e < E) atomicAdd(&lhist[er[e] >> 7], 1);        // int LDS atomic: native
    }
    __syncthreads();
    for (int b = threadIdx.x; b < nbuk; b += 256) {
        int c = lhist[b];
        int g = (c > 0) ? atomicAdd(&gcur[b], c) : 0;
        lpos[b] = b * BCAP + g;         // running write cursor for this block's chunk
    }
    __syncthreads();
    for (int j = 0; j < BK_EDGES; j += 256) {
        int e = e0 + j + threadIdx.x;
        if (e < E) {
            int r = er[e], b = r >> 7;
            int p = atomicAdd(&lpos[b], 1);
            if (p < (b + 1) * BCAP)     // capacity guard (statistically never)
                edata[p] = make_int2(((r & 127) << 17) | ec[e], __float_as_int(ev[e]));
        }
    }
}

// ---- pass 2: per-bucket CSR sort, fully in LDS, written back in place ----
__global__ __launch_bounds__(256) void k_csr(int2* __restrict__ edata,
                                             const int* __restrict__ gcur,
                                             int* __restrict__ rs, int* __restrict__ re) {
    __shared__ int2 sed[BCAP];          // 24 KB
    __shared__ int hist[BROWS];
    __shared__ int scan[BROWS];
    __shared__ int lcur[BROWS];
    int b = blockIdx.x, tid = threadIdx.x;
    int cnt = gcur[b]; if (cnt > BCAP) cnt = BCAP;
    int2* ed = edata + (long)b * BCAP;
    if (tid < BROWS) hist[tid] = 0;
    for (int i = tid; i < cnt; i += 256) sed[i] = ed[i];
    __syncthreads();
    for (int i = tid; i < cnt; i += 256) atomicAdd(&hist[sed[i].x >> 17], 1);
    __syncthreads();
    if (tid < BROWS) scan[tid] = hist[tid];
    __syncthreads();
    for (int off = 1; off < BROWS; off <<= 1) {             // Hillis-Steele inclusive
        int v = (tid < BROWS && tid >= off) ? scan[tid - off] : 0;
        __syncthreads();
        if (tid < BROWS) scan[tid] += v;
        __syncthreads();
    }
    if (tid < BROWS) {
        int excl = scan[tid] - hist[tid];
        lcur[tid] = excl;
        int row = b * BROWS + tid;                          // rs/re sized nbuk*BROWS
        rs[row] = b * BCAP + excl;
        re[row] = b * BCAP + excl + hist[tid];
    }
    __syncthreads();
    for (int i = tid; i < cnt; i += 256) {
        int2 v = sed[i];
        int p = atomicAdd(&lcur[v.x >> 17], 1);
        ed[p] = make_int2(v.x & 0x1FFFF, v.y);              // strip row bits: (col,val)
    }
}

// ---- gather: one wave per row; 4-deep MLP unroll breaks the load->fma chain ----
__global__ __launch_bounds__(256) void k_gather(const unsigned short* __restrict__ xb,
                                                const int2* __restrict__ edata,
                                                const int* __restrict__ rs,
                                                const int* __restrict__ re,
                                                unsigned short* __restrict__ aggb, int N) {
    int wave = threadIdx.x >> 6, lane = threadIdx.x & 63;
    int row = blockIdx.x * 4 + wave;
    if (row >= N) return;
    int beg = rs[row], end = re[row];
    float accx = 0.f, accy = 0.f;                   // dims {2*lane, 2*lane+1}
    const unsigned* xw = (const unsigned*)xb;       // xw[col*64 + lane] packs both dims
    for (int p = beg; p < end; p += 64) {
        int nc = end - p; if (nc > 64) nc = 64;
        int2 ed = (lane < nc) ? edata[p + lane] : make_int2(0, 0);
        int j = 0;
        for (; j + 4 <= nc; j += 4) {
            int c0 = __shfl(ed.x, j),     c1 = __shfl(ed.x, j + 1);
            int c2 = __shfl(ed.x, j + 2), c3 = __shfl(ed.x, j + 3);
            float v0 = __int_as_float(__shfl(ed.y, j));
            float v1 = __int_as_float(__shfl(ed.y, j + 1));
            float v2 = __int_as_float(__shfl(ed.y, j + 2));
            float v3 = __int_as_float(__shfl(ed.y, j + 3));
            unsigned u0 = xw[(long)c0 * 64 + lane];         // 4 independent loads in flight
            unsigned u1 = xw[(long)c1 * 64 + lane];
            unsigned u2 = xw[(long)c2 * 64 + lane];
            unsigned u3 = xw[(long)c3 * 64 + lane];
            accx += v0 * __uint_as_float(u0 << 16);
            accy += v0 * __uint_as_float(u0 & 0xffff0000u);
            accx += v1 * __uint_as_float(u1 << 16);
            accy += v1 * __uint_as_float(u1 & 0xffff0000u);
            accx += v2 * __uint_as_float(u2 << 16);
            accy += v2 * __uint_as_float(u2 & 0xffff0000u);
            accx += v3 * __uint_as_float(u3 << 16);
            accy += v3 * __uint_as_float(u3 & 0xffff0000u);
        }
        for (; j < nc; ++j) {
            int c = __shfl(ed.x, j);
            float v = __int_as_float(__shfl(ed.y, j));
            unsigned u = xw[(long)c * 64 + lane];
            accx += v * __uint_as_float(u << 16);
            accy += v * __uint_as_float(u & 0xffff0000u);
        }
    }
    *(ushort2*)(aggb + (long)row * DIM + lane * 2) = make_ushort2(f2bf(accx), f2bf(accy));
}

// ---- fused MFMA: out = leaky_relu([x+agg@W1^T, x*(agg@W1^T)] @ W2^T) ----
// 64 rows/block, 4 waves, wave-private 16-row strip; LDS only for C->A layout round-trip.
__global__ __launch_bounds__(256) void k_fused(const unsigned short* __restrict__ aggb,
                                               const unsigned short* __restrict__ inputb,
                                               const unsigned short* __restrict__ w1b,
                                               const unsigned short* __restrict__ w2b,
                                               float* __restrict__ out, int N) {
    __shared__ __align__(16) unsigned short sh[2 * 64 * 136];   // h0 | h1, rows padded to 136
    int w = threadIdx.x >> 6, lane = threadIdx.x & 63;
    int quad = lane >> 4, lq = lane & 15;
    int m0 = blockIdx.x * 64 + w * 16;

    // gemm1: A direct bf16 loads from aggb; B direct from global bf16 weights (L2-resident)
    short8 afr[4];
    {
        int row = m0 + lq; if (row >= N) row = N - 1;
#pragma unroll
        for (int kb = 0; kb < 4; ++kb)
            afr[kb] = *(const short8*)(aggb + (long)row * DIM + kb * 32 + quad * 8);
    }
    f32x4 neigh[8];
#pragma unroll
    for (int nt = 0; nt < 8; ++nt) {
        f32x4 c = {0.f, 0.f, 0.f, 0.f};
#pragma unroll
        for (int kb = 0; kb < 4; ++kb) {
            short8 b = *(const short8*)(w1b + (nt * 16 + lq) * DIM + kb * 32 + quad * 8);
            c = __builtin_amdgcn_mfma_f32_16x16x32_bf16(afr[kb], b, c, 0, 0, 0);
        }
        neigh[nt] = c;
    }

    // h phase: C-layout regs + bf16 x -> bf16 h -> wave-private LDS rows
    unsigned short* sh0 = sh;
    unsigned short* sh1 = sh + 64 * 136;
#pragma unroll
    for (int nt = 0; nt < 8; ++nt) {
#pragma unroll
        for (int rg = 0; rg < 4; ++rg) {
            int r = m0 + quad * 4 + rg;
            int rr = (r < N) ? r : (N - 1);
            float x = bf2f(inputb[(long)rr * DIM + nt * 16 + lq]);
            float nb = neigh[nt][rg];
            int off = (w * 16 + quad * 4 + rg) * 136 + nt * 16 + lq;
            sh0[off] = f2bf(x + nb);
            sh1[off] = f2bf(x * nb);
        }
    }

    // gemm2 (K=256 over two h halves) + leaky_relu epilogue, direct store
    int arow = (w * 16 + lq) * 136;
#pragma unroll
    for (int nt = 0; nt < 8; ++nt) {
        f32x4 c = {0.f, 0.f, 0.f, 0.f};
#pragma unroll
        for (int kb = 0; kb < 4; ++kb) {
            short8 a = *(const short8*)(sh0 + arow + kb * 32 + quad * 8);
            short8 b = *(const short8*)(w2b + (nt * 16 + lq) * 256 + kb * 32 + quad * 8);
            c = __builtin_amdgcn_mfma_f32_16x16x32_bf16(a, b, c, 0, 0, 0);
        }
#pragma unroll
        for (int kb = 0; kb < 4; ++kb) {
            short8 a = *(const short8*)(sh1 + arow + kb * 32 + quad * 8);
            short8 b = *(const short8*)(w2b + (nt * 16 + lq) * 256 + 128 + kb * 32 + quad * 8);
            c = __builtin_amdgcn_mfma_f32_16x16x32_bf16(a, b, c, 0, 0, 0);
        }
#pragma unroll
        for (int rg = 0; rg < 4; ++rg) {
            int r = m0 + quad * 4 + rg;
            if (r < N) {
                float v = c[rg];
                v = (v > 0.f) ? v : 0.01f * v;
                out[(long)r * DIM + nt * 16 + lq] = v;
            }
        }
    }
}

extern "C" void kernel_launch(void* const* d_in, const int* in_sizes, int n_in,
                              void* d_out, int out_size, void* d_ws, size_t ws_size,
                              hipStream_t stream) {
    const float* input = (const float*)d_in[0];
    const int*   er    = (const int*)d_in[1];
    const int*   ec    = (const int*)d_in[2];
    const float* ev    = (const float*)d_in[3];
    const float* W1    = (const float*)d_in[4];
    const float* W2    = (const float*)d_in[5];
    int N = in_sizes[0] / DIM;      // 100000
    int E = in_sizes[1];            // 1600000
    float* out = (float*)d_out;
    int nbuk = (N + BROWS - 1) / BROWS;     // 782

    // ---- workspace layout (~71 MB, all chunks 16B-aligned) ----
    int* ws = (int*)d_ws;
    int* gcur = ws;                                                      // nbuk ints (pad 1024)
    int2* edata = (int2*)(ws + 1024);                                    // nbuk*BCAP int2
    int* rs = (int*)(edata + (long)nbuk * BCAP);                         // nbuk*BROWS ints
    int* re = rs + (long)nbuk * BROWS;                                   // nbuk*BROWS ints
    unsigned short* w1b = (unsigned short*)(re + (long)nbuk * BROWS);    // 16384 bf16
    unsigned short* w2b = w1b + 16384;                                   // 32768 bf16
    unsigned short* inputb = w2b + 32768;                                // N*DIM bf16
    unsigned short* aggb = inputb + (long)N * DIM;                       // N*DIM bf16

    int n4 = N * (DIM / 4);
    int nCvt = (n4 + 255) / 256;
    int nZero = (nbuk + 255) / 256;
    k_pre<<<nCvt + 192 + nZero, 256, 0, stream>>>(
        (const float4*)input, W1, W2, inputb, w1b, w2b, gcur, n4, nCvt, nbuk);

    k_bucket<<<(E + BK_EDGES - 1) / BK_EDGES, 256, 0, stream>>>(
        er, ec, ev, gcur, edata, E, nbuk);

    k_csr<<<nbuk, 256, 0, stream>>>(edata, gcur, rs, re);

    k_gather<<<(N + 3) / 4, 256, 0, stream>>>(inputb, edata, rs, re, aggb, N);

    k_fused<<<(N + 63) / 64, 256, 0, stream>>>(aggb, inputb, w1b, w2b, out, N);
}